// Round 3
// baseline (694.890 us; speedup 1.0000x reference)
//
#include <hip/hip_runtime.h>
#include <math.h>

#define NROWS 2000000
#define IN_DIM 64
#define HID 128
#define NTILES (NROWS / 16)   // 125000 tiles of 16 rows
#define BLOCK 512
#define NBLK 512
#define WPB (BLOCK / 64)      // 8 waves per block

typedef __bf16 bf16x8 __attribute__((ext_vector_type(8)));
typedef float f32x4 __attribute__((ext_vector_type(4)));

// tanh(a) = 1 - 2/(exp(2a)+1); NaN-free as a -> +/-inf (exp->inf, rcp->0)
__device__ __forceinline__ float tanh_fast(float a) {
    float p = __expf(2.0f * a);
    float r = __builtin_amdgcn_rcpf(p + 1.0f);
    return fmaf(-2.0f, r, 1.0f);
}

// Split 8 fp32 into hi/lo bf16: v = h + l + O(2^-18 |v|)
__device__ __forceinline__ void split8(f32x4 a, f32x4 b, bf16x8& h, bf16x8& l) {
    #pragma unroll
    for (int j = 0; j < 4; j++) {
        __bf16 hb = (__bf16)a[j];
        h[j] = hb;
        l[j] = (__bf16)(a[j] - (float)hb);
    }
    #pragma unroll
    for (int j = 0; j < 4; j++) {
        __bf16 hb = (__bf16)b[j];
        h[4 + j] = hb;
        l[4 + j] = (__bf16)(b[j] - (float)hb);
    }
}

__global__ void zero_sums_kernel(float* g) {
    if (threadIdx.x < 2) g[threadIdx.x] = 0.0f;
}

__global__ __launch_bounds__(BLOCK, 4) void fused_mfma_kernel(
    const float* __restrict__ x, const int* __restrict__ T,
    const float* __restrict__ W1, const float* __restrict__ b1,
    const float* __restrict__ W2, const float* __restrict__ b2,
    float* __restrict__ e_out, float* __restrict__ gsums)
{
    // W1 fragments (hi/lo bf16), shared by all waves: [hl][t][c][lane][8] = 32 KB
    __shared__ __bf16 wlds[2][8][2][64][8];
    // per-wave x tile staging buffer (16 rows x 64 f32 = 4 KB each) = 32 KB
    __shared__ float xlds[WPB][1024];

    const int lane = threadIdx.x & 63;
    const int wv   = threadIdx.x >> 6;
    const int c16  = lane & 15;   // A-row / B-col residue
    const int g4   = lane >> 4;   // k-octet / C row-group

    // ---- one-time: build W1 hi/lo fragments in LDS (wave wv handles t = wv) ----
    {
        const int t = wv;
        const int n = t * 16 + c16;
        #pragma unroll
        for (int c = 0; c < 2; c++) {
            const int kb = c * 32 + g4 * 8;
            bf16x8 h, l;
            #pragma unroll
            for (int j = 0; j < 8; j++) {
                float w = W1[n * IN_DIM + kb + j];
                __bf16 hb = (__bf16)w;
                h[j] = hb;
                l[j] = (__bf16)(w - (float)hb);
            }
            *(bf16x8*)&wlds[0][t][c][lane][0] = h;
            *(bf16x8*)&wlds[1][t][c][lane][0] = l;
        }
    }
    __syncthreads();   // only barrier; waves independent afterwards

    float b1v[8], w2v[8];
    #pragma unroll
    for (int t = 0; t < 8; t++) {
        b1v[t] = b1[t * 16 + c16];
        w2v[t] = W2[t * 16 + c16];
    }
    const float b2v = b2[0];

    float* xb = xlds[wv];
    const int gwave = blockIdx.x * WPB + wv;
    const int nwave = NBLK * WPB;     // 4096 waves, all resident

    float ls0 = 0.f, ls1 = 0.f;

    // ---- prologue: coalesced load of first tile -> regs -> swizzled LDS ----
    int tile = gwave;
    f32x4 g0, g1, g2, g3;
    {
        const float* xs = x + (size_t)tile * 1024 + lane * 4;
        g0 = *(const f32x4*)(xs);
        g1 = *(const f32x4*)(xs + 256);
        g2 = *(const f32x4*)(xs + 512);
        g3 = *(const f32x4*)(xs + 768);
        const int l4 = lane * 4;
        // swizzle: float-index ^= (row & 7) << 2  (row = 64-float stripes)
        *(f32x4*)&xb[(0 * 256 + l4) ^ ((((0 * 256 + l4) >> 6) & 7) << 2)] = g0;
        *(f32x4*)&xb[(1 * 256 + l4) ^ ((((1 * 256 + l4) >> 6) & 7) << 2)] = g1;
        *(f32x4*)&xb[(2 * 256 + l4) ^ ((((2 * 256 + l4) >> 6) & 7) << 2)] = g2;
        *(f32x4*)&xb[(3 * 256 + l4) ^ ((((3 * 256 + l4) >> 6) & 7) << 2)] = g3;
    }

    for (; tile < NTILES; tile += nwave) {
        const int nt = tile + nwave;
        if (nt < NTILES) {   // issue next tile's coalesced loads early
            const float* xs = x + (size_t)nt * 1024 + lane * 4;
            g0 = *(const f32x4*)(xs);
            g1 = *(const f32x4*)(xs + 256);
            g2 = *(const f32x4*)(xs + 512);
            g3 = *(const f32x4*)(xs + 768);
        }

        // ---- read current tile's A-fragments from swizzled LDS ----
        const int sw = (c16 & 7) << 2;
        const int base = c16 * 64 + g4 * 8;
        f32x4 a0 = *(const f32x4*)&xb[(base + 0)  ^ sw];
        f32x4 a1 = *(const f32x4*)&xb[(base + 4)  ^ sw];
        f32x4 a2 = *(const f32x4*)&xb[(base + 32) ^ sw];
        f32x4 a3 = *(const f32x4*)&xb[(base + 36) ^ sw];
        bf16x8 xh0, xl0, xh1, xl1;
        split8(a0, a1, xh0, xl0);
        split8(a2, a3, xh1, xl1);

        // ---- 3-term bf16-split MFMA: x@W1.T (error ~2^-18, negligible here) ----
        f32x4 acc[8];
        #pragma unroll
        for (int t = 0; t < 8; t++) acc[t] = (f32x4){0.f, 0.f, 0.f, 0.f};
        #pragma unroll
        for (int t = 0; t < 8; t++) {
            bf16x8 wh0 = *(const bf16x8*)&wlds[0][t][0][lane][0];
            bf16x8 wl0 = *(const bf16x8*)&wlds[1][t][0][lane][0];
            bf16x8 wh1 = *(const bf16x8*)&wlds[0][t][1][lane][0];
            bf16x8 wl1 = *(const bf16x8*)&wlds[1][t][1][lane][0];
            acc[t] = __builtin_amdgcn_mfma_f32_16x16x32_bf16(xh0, wh0, acc[t], 0, 0, 0);
            acc[t] = __builtin_amdgcn_mfma_f32_16x16x32_bf16(xl0, wh0, acc[t], 0, 0, 0);
            acc[t] = __builtin_amdgcn_mfma_f32_16x16x32_bf16(xh0, wl0, acc[t], 0, 0, 0);
            acc[t] = __builtin_amdgcn_mfma_f32_16x16x32_bf16(xh1, wh1, acc[t], 0, 0, 0);
            acc[t] = __builtin_amdgcn_mfma_f32_16x16x32_bf16(xl1, wh1, acc[t], 0, 0, 0);
            acc[t] = __builtin_amdgcn_mfma_f32_16x16x32_bf16(xh1, wl1, acc[t], 0, 0, 0);
        }

        // ---- epilogue: bias + tanh + W2 partials ----
        // C layout: lane holds h[row = g4*4 + r][col = t*16 + c16]
        float sp0 = 0.f, sp1 = 0.f, sp2 = 0.f, sp3 = 0.f;
        #pragma unroll
        for (int t = 0; t < 8; t++) {
            sp0 = fmaf(tanh_fast(acc[t][0] + b1v[t]), w2v[t], sp0);
            sp1 = fmaf(tanh_fast(acc[t][1] + b1v[t]), w2v[t], sp1);
            sp2 = fmaf(tanh_fast(acc[t][2] + b1v[t]), w2v[t], sp2);
            sp3 = fmaf(tanh_fast(acc[t][3] + b1v[t]), w2v[t], sp3);
        }
        #pragma unroll
        for (int m = 1; m < 16; m <<= 1) {
            sp0 += __shfl_xor(sp0, m, 16);
            sp1 += __shfl_xor(sp1, m, 16);
            sp2 += __shfl_xor(sp2, m, 16);
            sp3 += __shfl_xor(sp3, m, 16);
        }
        if (c16 < 4) {   // 16 lanes own the 16 rows: row = g4*4 + c16
            float svv = (c16 == 0) ? sp0 : (c16 == 1) ? sp1 : (c16 == 2) ? sp2 : sp3;
            float e = __expf(svv + b2v);
            int row = tile * 16 + g4 * 4 + c16;
            e_out[row] = e;
            if (T[row] == 0) ls0 += e; else ls1 += e;
        }

        // ---- park next tile in LDS (vmcnt drain covered by compute above) ----
        if (nt < NTILES) {
            const int l4 = lane * 4;
            *(f32x4*)&xb[(0 * 256 + l4) ^ ((((0 * 256 + l4) >> 6) & 7) << 2)] = g0;
            *(f32x4*)&xb[(1 * 256 + l4) ^ ((((1 * 256 + l4) >> 6) & 7) << 2)] = g1;
            *(f32x4*)&xb[(2 * 256 + l4) ^ ((((2 * 256 + l4) >> 6) & 7) << 2)] = g2;
            *(f32x4*)&xb[(3 * 256 + l4) ^ ((((3 * 256 + l4) >> 6) & 7) << 2)] = g3;
        }
    }

    // per-wave reduce, then one atomic pair per wave (4096 waves total)
    #pragma unroll
    for (int off = 32; off > 0; off >>= 1) {
        ls0 += __shfl_down(ls0, off, 64);
        ls1 += __shfl_down(ls1, off, 64);
    }
    if (lane == 0) {
        atomicAdd(&gsums[0], ls0);
        atomicAdd(&gsums[1], ls1);
    }
}

__global__ __launch_bounds__(256) void normalize_kernel(
    float* __restrict__ e_out, const int* __restrict__ T,
    const float* __restrict__ gsums)
{
    const float inv0 = 1.0f / gsums[0];
    const float inv1 = 1.0f / gsums[1];
    const int n4 = NROWS / 4;
    const int stride = gridDim.x * blockDim.x;
    for (int i = blockIdx.x * blockDim.x + threadIdx.x; i < n4; i += stride) {
        float4 e = reinterpret_cast<const float4*>(e_out)[i];
        int4  t = reinterpret_cast<const int4*>(T)[i];
        e.x *= (t.x == 0) ? inv0 : inv1;
        e.y *= (t.y == 0) ? inv0 : inv1;
        e.z *= (t.z == 0) ? inv0 : inv1;
        e.w *= (t.w == 0) ? inv0 : inv1;
        reinterpret_cast<float4*>(e_out)[i] = e;
    }
}

extern "C" void kernel_launch(void* const* d_in, const int* in_sizes, int n_in,
                              void* d_out, int out_size, void* d_ws, size_t ws_size,
                              hipStream_t stream) {
    const float* x  = (const float*)d_in[0];
    const int*   T  = (const int*)d_in[1];
    const float* W1 = (const float*)d_in[2];
    const float* b1 = (const float*)d_in[3];
    const float* W2 = (const float*)d_in[4];
    const float* b2 = (const float*)d_in[5];
    float* e_out = (float*)d_out;
    float* gsums = (float*)d_ws;

    zero_sums_kernel<<<1, 64, 0, stream>>>(gsums);

    // 512 blocks x 512 thr = 4096 waves; 64 KB LDS + <=128 VGPR ->
    // 2 blocks/CU, 16 waves/CU (4/SIMD), all resident.
    fused_mfma_kernel<<<NBLK, BLOCK, 0, stream>>>(x, T, W1, b1, W2, b2, e_out, gsums);

    normalize_kernel<<<2048, 256, 0, stream>>>(e_out, T, gsums);
}

// Round 4
// 213.326 us; speedup vs baseline: 3.2574x; 3.2574x over previous
//
#include <hip/hip_runtime.h>
#include <math.h>

#define NROWS 2000000
#define IN_DIM 64
#define HID 128
#define NTILES (NROWS / 16)   // 125000 tiles of 16 rows
#define BLOCK 512
#define NBLK 512
#define WPB (BLOCK / 64)      // 8 waves per block

typedef __bf16 bf16x8 __attribute__((ext_vector_type(8)));
typedef float f32x4 __attribute__((ext_vector_type(4)));

// tanh(a) = 1 - 2/(exp(2a)+1); NaN-free as a -> +/-inf (exp->inf, rcp->0)
__device__ __forceinline__ float tanh_fast(float a) {
    float p = __expf(2.0f * a);
    float r = __builtin_amdgcn_rcpf(p + 1.0f);
    return fmaf(-2.0f, r, 1.0f);
}

// Split 8 fp32 into hi/lo bf16: v = h + l + O(2^-18 |v|)
__device__ __forceinline__ void split8(f32x4 a, f32x4 b, bf16x8& h, bf16x8& l) {
    #pragma unroll
    for (int j = 0; j < 4; j++) {
        __bf16 hb = (__bf16)a[j];
        h[j] = hb;
        l[j] = (__bf16)(a[j] - (float)hb);
    }
    #pragma unroll
    for (int j = 0; j < 4; j++) {
        __bf16 hb = (__bf16)b[j];
        h[4 + j] = hb;
        l[4 + j] = (__bf16)(b[j] - (float)hb);
    }
}

__global__ void zero_sums_kernel(float* g) {
    if (threadIdx.x < 2) g[threadIdx.x] = 0.0f;
}

// launch_bounds(512, 2): under CUDA semantics (min 2 blocks/CU -> 16 waves/CU)
// the VGPR cap is 128; under HIP waves-per-EU semantics the cap is 256.
// Either way >= our ~117-reg live set -> NO SPILL (round 3's (512,4) forced a
// 64-reg cap and 600 MB of scratch writes). LDS (64 KB/block) pins occupancy
// at 2 blocks/CU = 4 waves/SIMD regardless.
__global__ __launch_bounds__(BLOCK, 2) void fused_mfma_kernel(
    const float* __restrict__ x, const int* __restrict__ T,
    const float* __restrict__ W1, const float* __restrict__ b1,
    const float* __restrict__ W2, const float* __restrict__ b2,
    float* __restrict__ e_out, float* __restrict__ gsums)
{
    // W1 fragments (hi/lo bf16), shared by all waves: [hl][t][c][lane][8] = 32 KB
    __shared__ __bf16 wlds[2][8][2][64][8];
    // per-wave x tile staging buffer (16 rows x 64 f32 = 4 KB each) = 32 KB
    __shared__ float xlds[WPB][1024];

    const int lane = threadIdx.x & 63;
    const int wv   = threadIdx.x >> 6;
    const int c16  = lane & 15;   // A-row / B-col residue
    const int g4   = lane >> 4;   // k-octet / C row-group

    // ---- one-time: build W1 hi/lo fragments in LDS (wave wv handles t = wv) ----
    {
        const int t = wv;
        const int n = t * 16 + c16;
        #pragma unroll
        for (int c = 0; c < 2; c++) {
            const int kb = c * 32 + g4 * 8;
            bf16x8 h, l;
            #pragma unroll
            for (int j = 0; j < 8; j++) {
                float w = W1[n * IN_DIM + kb + j];
                __bf16 hb = (__bf16)w;
                h[j] = hb;
                l[j] = (__bf16)(w - (float)hb);
            }
            *(bf16x8*)&wlds[0][t][c][lane][0] = h;
            *(bf16x8*)&wlds[1][t][c][lane][0] = l;
        }
    }
    __syncthreads();   // only barrier; waves independent afterwards

    float b1v[8], w2v[8];
    #pragma unroll
    for (int t = 0; t < 8; t++) {
        b1v[t] = b1[t * 16 + c16];
        w2v[t] = W2[t * 16 + c16];
    }
    const float b2v = b2[0];

    float* xb = xlds[wv];
    const int gwave = blockIdx.x * WPB + wv;
    const int nwave = NBLK * WPB;     // 4096 waves, all resident

    float ls0 = 0.f, ls1 = 0.f;

    // ---- prologue: coalesced load of first tile -> regs -> swizzled LDS ----
    int tile = gwave;
    f32x4 g0, g1, g2, g3;
    {
        const float* xs = x + (size_t)tile * 1024 + lane * 4;
        g0 = *(const f32x4*)(xs);
        g1 = *(const f32x4*)(xs + 256);
        g2 = *(const f32x4*)(xs + 512);
        g3 = *(const f32x4*)(xs + 768);
        const int l4 = lane * 4;
        // swizzle: float-index ^= (row & 7) << 2  (row = 64-float stripes)
        *(f32x4*)&xb[(0 * 256 + l4) ^ ((((0 * 256 + l4) >> 6) & 7) << 2)] = g0;
        *(f32x4*)&xb[(1 * 256 + l4) ^ ((((1 * 256 + l4) >> 6) & 7) << 2)] = g1;
        *(f32x4*)&xb[(2 * 256 + l4) ^ ((((2 * 256 + l4) >> 6) & 7) << 2)] = g2;
        *(f32x4*)&xb[(3 * 256 + l4) ^ ((((3 * 256 + l4) >> 6) & 7) << 2)] = g3;
    }

    for (; tile < NTILES; tile += nwave) {
        const int nt = tile + nwave;
        if (nt < NTILES) {   // issue next tile's coalesced loads early
            const float* xs = x + (size_t)nt * 1024 + lane * 4;
            g0 = *(const f32x4*)(xs);
            g1 = *(const f32x4*)(xs + 256);
            g2 = *(const f32x4*)(xs + 512);
            g3 = *(const f32x4*)(xs + 768);
        }

        // ---- read current tile's A-fragments from swizzled LDS ----
        const int sw = (c16 & 7) << 2;
        const int base = c16 * 64 + g4 * 8;
        f32x4 a0 = *(const f32x4*)&xb[(base + 0)  ^ sw];
        f32x4 a1 = *(const f32x4*)&xb[(base + 4)  ^ sw];
        f32x4 a2 = *(const f32x4*)&xb[(base + 32) ^ sw];
        f32x4 a3 = *(const f32x4*)&xb[(base + 36) ^ sw];
        bf16x8 xh0, xl0, xh1, xl1;
        split8(a0, a1, xh0, xl0);
        split8(a2, a3, xh1, xl1);

        // ---- 3-term bf16-split MFMA: x@W1.T (error ~2^-18, negligible here) ----
        f32x4 acc[8];
        #pragma unroll
        for (int t = 0; t < 8; t++) acc[t] = (f32x4){0.f, 0.f, 0.f, 0.f};
        #pragma unroll
        for (int t = 0; t < 8; t++) {
            bf16x8 wh0 = *(const bf16x8*)&wlds[0][t][0][lane][0];
            bf16x8 wl0 = *(const bf16x8*)&wlds[1][t][0][lane][0];
            bf16x8 wh1 = *(const bf16x8*)&wlds[0][t][1][lane][0];
            bf16x8 wl1 = *(const bf16x8*)&wlds[1][t][1][lane][0];
            acc[t] = __builtin_amdgcn_mfma_f32_16x16x32_bf16(xh0, wh0, acc[t], 0, 0, 0);
            acc[t] = __builtin_amdgcn_mfma_f32_16x16x32_bf16(xl0, wh0, acc[t], 0, 0, 0);
            acc[t] = __builtin_amdgcn_mfma_f32_16x16x32_bf16(xh0, wl0, acc[t], 0, 0, 0);
            acc[t] = __builtin_amdgcn_mfma_f32_16x16x32_bf16(xh1, wh1, acc[t], 0, 0, 0);
            acc[t] = __builtin_amdgcn_mfma_f32_16x16x32_bf16(xl1, wh1, acc[t], 0, 0, 0);
            acc[t] = __builtin_amdgcn_mfma_f32_16x16x32_bf16(xh1, wl1, acc[t], 0, 0, 0);
        }

        // ---- epilogue: bias + tanh + W2 partials ----
        // C layout: lane holds h[row = g4*4 + r][col = t*16 + c16]
        float sp0 = 0.f, sp1 = 0.f, sp2 = 0.f, sp3 = 0.f;
        #pragma unroll
        for (int t = 0; t < 8; t++) {
            sp0 = fmaf(tanh_fast(acc[t][0] + b1v[t]), w2v[t], sp0);
            sp1 = fmaf(tanh_fast(acc[t][1] + b1v[t]), w2v[t], sp1);
            sp2 = fmaf(tanh_fast(acc[t][2] + b1v[t]), w2v[t], sp2);
            sp3 = fmaf(tanh_fast(acc[t][3] + b1v[t]), w2v[t], sp3);
        }
        #pragma unroll
        for (int m = 1; m < 16; m <<= 1) {
            sp0 += __shfl_xor(sp0, m, 16);
            sp1 += __shfl_xor(sp1, m, 16);
            sp2 += __shfl_xor(sp2, m, 16);
            sp3 += __shfl_xor(sp3, m, 16);
        }
        if (c16 < 4) {   // 16 lanes own the 16 rows: row = g4*4 + c16
            float svv = (c16 == 0) ? sp0 : (c16 == 1) ? sp1 : (c16 == 2) ? sp2 : sp3;
            float e = __expf(svv + b2v);
            int row = tile * 16 + g4 * 4 + c16;
            e_out[row] = e;
            if (T[row] == 0) ls0 += e; else ls1 += e;
        }

        // ---- park next tile in LDS (vmcnt drain covered by compute above) ----
        if (nt < NTILES) {
            const int l4 = lane * 4;
            *(f32x4*)&xb[(0 * 256 + l4) ^ ((((0 * 256 + l4) >> 6) & 7) << 2)] = g0;
            *(f32x4*)&xb[(1 * 256 + l4) ^ ((((1 * 256 + l4) >> 6) & 7) << 2)] = g1;
            *(f32x4*)&xb[(2 * 256 + l4) ^ ((((2 * 256 + l4) >> 6) & 7) << 2)] = g2;
            *(f32x4*)&xb[(3 * 256 + l4) ^ ((((3 * 256 + l4) >> 6) & 7) << 2)] = g3;
        }
    }

    // per-wave reduce, then one atomic pair per wave (4096 waves total)
    #pragma unroll
    for (int off = 32; off > 0; off >>= 1) {
        ls0 += __shfl_down(ls0, off, 64);
        ls1 += __shfl_down(ls1, off, 64);
    }
    if (lane == 0) {
        atomicAdd(&gsums[0], ls0);
        atomicAdd(&gsums[1], ls1);
    }
}

__global__ __launch_bounds__(256) void normalize_kernel(
    float* __restrict__ e_out, const int* __restrict__ T,
    const float* __restrict__ gsums)
{
    const float inv0 = 1.0f / gsums[0];
    const float inv1 = 1.0f / gsums[1];
    const int n4 = NROWS / 4;
    const int stride = gridDim.x * blockDim.x;
    for (int i = blockIdx.x * blockDim.x + threadIdx.x; i < n4; i += stride) {
        float4 e = reinterpret_cast<const float4*>(e_out)[i];
        int4  t = reinterpret_cast<const int4*>(T)[i];
        e.x *= (t.x == 0) ? inv0 : inv1;
        e.y *= (t.y == 0) ? inv0 : inv1;
        e.z *= (t.z == 0) ? inv0 : inv1;
        e.w *= (t.w == 0) ? inv0 : inv1;
        reinterpret_cast<float4*>(e_out)[i] = e;
    }
}

extern "C" void kernel_launch(void* const* d_in, const int* in_sizes, int n_in,
                              void* d_out, int out_size, void* d_ws, size_t ws_size,
                              hipStream_t stream) {
    const float* x  = (const float*)d_in[0];
    const int*   T  = (const int*)d_in[1];
    const float* W1 = (const float*)d_in[2];
    const float* b1 = (const float*)d_in[3];
    const float* W2 = (const float*)d_in[4];
    const float* b2 = (const float*)d_in[5];
    float* e_out = (float*)d_out;
    float* gsums = (float*)d_ws;

    zero_sums_kernel<<<1, 64, 0, stream>>>(gsums);

    // 512 blocks x 512 thr = 4096 waves; 64 KB LDS/block -> 2 blocks/CU,
    // 16 waves/CU (4/SIMD), all resident; grid-stride statically partitioned.
    fused_mfma_kernel<<<NBLK, BLOCK, 0, stream>>>(x, T, W1, b1, W2, b2, e_out, gsums);

    normalize_kernel<<<2048, 256, 0, stream>>>(e_out, T, gsums);
}